// Round 2
// baseline (2076.813 us; speedup 1.0000x reference)
//
#include <hip/hip_runtime.h>
#include <hip/hip_bf16.h>

typedef __hip_bfloat16 bf16;
typedef short  sv4 __attribute__((ext_vector_type(4)));
typedef short  sv8 __attribute__((ext_vector_type(8)));
typedef float  f32x4 __attribute__((ext_vector_type(4)));

#define CH      64
#define DWC     128
#define SDIM    512
#define SPATIAL (64*64*64)     // 262144
#define NB      2
#define NVOX    (NB*SPATIAL)

// f32 workspace offsets (floats), area starts at d_ws + 2*H_BYTES
#define OFF_SMOD   0
#define OFF_POOLED 256
#define OFF_GATE   512
#define OFF_PB1    768     // (b1p, w1s) pairs [128]
#define OFF_PB4    1024    // (b4p, w4s) pairs [128]
#define OFF_PB35   1280    // (b3, beta, gamma, b5) quads [64]
#define OFF_MODWT  1536    // [27][128]
#define OFF_U16    5120    // start of bf16 weight area (in floats)
// u16 offsets from (short*)(wsf + OFF_U16)
#define U16_W1B 0          // [128][64]
#define U16_W3G 8192       // [2][64][128]  (gate-folded, per batch)
#define U16_W4B 24576      // [128][64]
#define U16_W5B 32768      // [64][128]

#define H_ELEMS ((size_t)NB * DWC * SPATIAL)
#define H_BYTES (H_ELEMS * 2)                 // 134,217,728

__device__ __forceinline__ float b2f(short u) {
    return __uint_as_float(((unsigned)(unsigned short)u) << 16);
}
__device__ __forceinline__ short f2bs(float f) {
    __hip_bfloat16 h = __float2bfloat16(f);
    return __builtin_bit_cast(short, h);
}
__device__ __forceinline__ float gelu_f(float x) {
    return 0.5f * x * (1.0f + erff(x * 0.70710678118654752f));
}

// ---------------- K0: prep -----------------------------------------------
__global__ void prep_kernel(const float* __restrict__ style,
                            const float* __restrict__ w1, const float* __restrict__ b1,
                            const float* __restrict__ mod_w,
                            const float* __restrict__ style_w, const float* __restrict__ style_b,
                            const float* __restrict__ b3,
                            const float* __restrict__ w4, const float* __restrict__ b4,
                            const float* __restrict__ w5, const float* __restrict__ b5,
                            const float* __restrict__ ln1w, const float* __restrict__ ln1b,
                            const float* __restrict__ ln2w, const float* __restrict__ ln2b,
                            const float* __restrict__ beta, const float* __restrict__ gamma,
                            float* __restrict__ wsf) {
    int t = threadIdx.x;   // 256 threads, 1 block
    short* w16 = (short*)(wsf + OFF_U16);
    {   // s*demod per (b, ch); zero pooled
        int b = t >> 7, ch = t & 127;
        float s = style_b[ch];
        for (int i = 0; i < SDIM; ++i) s = fmaf(style[b*SDIM + i], style_w[ch*SDIM + i], s);
        float k2 = 0.f;
        for (int j = 0; j < 27; ++j) { float w = mod_w[ch*27 + j]; k2 = fmaf(w, w, k2); }
        wsf[OFF_SMOD + t]   = s * rsqrtf(fmaf(k2, s*s, 1e-8f));
        wsf[OFF_POOLED + t] = 0.f;
    }
    if (t < DWC) {
        float bb1 = b1[t], ss1 = 0.f, bb4 = b4[t], ss4 = 0.f;
        for (int c = 0; c < CH; ++c) {
            bb1 = fmaf(w1[t*CH + c], ln1b[c], bb1);
            ss1 = fmaf(w1[t*CH + c], ln1w[c], ss1);
            bb4 = fmaf(w4[t*CH + c], ln2b[c], bb4);
            ss4 = fmaf(w4[t*CH + c], ln2w[c], ss4);
        }
        wsf[OFF_PB1 + 2*t] = bb1; wsf[OFF_PB1 + 2*t + 1] = ss1;
        wsf[OFF_PB4 + 2*t] = bb4; wsf[OFF_PB4 + 2*t + 1] = ss4;
    }
    if (t < CH) {
        wsf[OFF_PB35 + 4*t + 0] = b3[t];
        wsf[OFF_PB35 + 4*t + 1] = beta[t];
        wsf[OFF_PB35 + 4*t + 2] = gamma[t];
        wsf[OFF_PB35 + 4*t + 3] = b5[t];
    }
    for (int idx = t; idx < 27*DWC; idx += 256) {   // mod_w transpose [27][128]
        int k = idx >> 7, c = idx & 127;
        wsf[OFF_MODWT + idx] = mod_w[c*27 + k];
    }
    for (int idx = t; idx < DWC*CH; idx += 256) {   // bf16 weights
        int c = idx & 63;
        w16[U16_W1B + idx] = f2bs(w1[idx] * ln1w[c]);
        w16[U16_W4B + idx] = f2bs(w4[idx] * ln2w[c]);
        w16[U16_W5B + idx] = f2bs(w5[idx]);         // [64][128] row-major = [M][K]
    }
}

// ---------------- K1: LN1 + pw1 (MFMA) -> h [B][16g][v][8] bf16 ---------
__global__ __launch_bounds__(256) void lnpw1_kernel(const float* __restrict__ inp,
                                                    const float* __restrict__ wsf,
                                                    sv8* __restrict__ h) {
    __shared__ short ht[4][16*136];
    int blk = blockIdx.x;
    int b = blk >> 12;
    int vb = ((blk & 4095) << 6) + ((threadIdx.x >> 6) << 4);
    int lane = threadIdx.x & 63;
    int col = lane & 15, grp = lane >> 4;

    const float* xp = inp + (size_t)b * CH * SPATIAL + vb + col;
    float xv[16];
    float sum = 0.f, ssq = 0.f;
    #pragma unroll
    for (int e = 0; e < 16; ++e) {
        int k = ((e >> 3) << 5) + (grp << 3) + (e & 7);
        float t = xp[(size_t)k * SPATIAL];
        xv[e] = t; sum += t; ssq = fmaf(t, t, ssq);
    }
    sum += __shfl_xor(sum, 16); sum += __shfl_xor(sum, 32);
    ssq += __shfl_xor(ssq, 16); ssq += __shfl_xor(ssq, 32);
    float m   = sum * (1.f/64.f);
    float var = fmaxf((ssq - 64.f*m*m) * (1.f/63.f), 0.f);
    float inv = 1.f / (sqrtf(var) + 1e-6f);

    sv8 xb[2];
    #pragma unroll
    for (int ks = 0; ks < 2; ++ks)
        #pragma unroll
        for (int i = 0; i < 8; ++i) xb[ks][i] = f2bs(xv[ks*8 + i]);

    const sv8* W1 = (const sv8*)((const short*)(wsf + OFF_U16) + U16_W1B);
    f32x4 acc[8] = {};
    #pragma unroll
    for (int mt = 0; mt < 8; ++mt) {
        const sv8* wr = W1 + (mt*16 + col) * 8;
        acc[mt] = __builtin_amdgcn_mfma_f32_16x16x32_bf16(wr[grp],     xb[0], acc[mt], 0, 0, 0);
        acc[mt] = __builtin_amdgcn_mfma_f32_16x16x32_bf16(wr[grp + 4], xb[1], acc[mt], 0, 0, 0);
    }

    const float2* pb1 = (const float2*)(wsf + OFF_PB1);
    short* hw = &ht[threadIdx.x >> 6][0];
    #pragma unroll
    for (int mt = 0; mt < 8; ++mt) {
        sv4 p;
        #pragma unroll
        for (int r = 0; r < 4; ++r) {
            int f = mt*16 + 4*grp + r;
            float2 pb = pb1[f];
            p[r] = f2bs(pb.x + inv*(acc[mt][r] - m*pb.y));
        }
        *(sv4*)(hw + col*136 + mt*16 + 4*grp) = p;
    }
    #pragma unroll
    for (int gq = 0; gq < 4; ++gq) {
        int g = gq*4 + grp;
        sv8 vrow = *(const sv8*)(hw + col*136 + g*8);
        h[((size_t)(b*16 + g)) * SPATIAL + vb + col] = vrow;
    }
}

// ---------------- K2: depthwise 3x3x3 + mod + GELU -> a, pooled ---------
__global__ __launch_bounds__(256) void conv_kernel(const sv8* __restrict__ h,
                                                   const float* __restrict__ mod_b,
                                                   const float* __restrict__ wsf,
                                                   sv8* __restrict__ a,
                                                   float* __restrict__ pooled) {
    __shared__ sv8 tile[36*67];
    int blk = blockIdx.x;                   // [0, 8192)
    int b  = blk >> 12;
    int g  = (blk >> 8) & 15;
    int d0 = ((blk >> 4) & 15) << 2;
    int h0 = (blk & 15) << 2;
    int tid = threadIdx.x;
    int dl = tid >> 6, hh = (tid >> 4) & 3, wq = tid & 15;
    int wx0 = wq << 2;
    int lane = tid & 63;

    const sv8* hsrc = h + (size_t)(b*16 + g) * SPATIAL;
    for (int i = tid; i < 2376; i += 256) {
        int dd = i / 396; int r = i - dd*396;
        int hy = r / 66;  int wxc = r - hy*66;
        int gd = d0 - 1 + dd, gh = h0 - 1 + hy, wx = wxc - 1;
        sv8 val = {0,0,0,0,0,0,0,0};
        if ((unsigned)gd < 64u && (unsigned)gh < 64u && (unsigned)wx < 64u)
            val = hsrc[gd*4096 + gh*64 + wx];
        tile[(dd*6 + hy)*67 + wxc] = val;
    }
    __syncthreads();

    float acc[4][8] = {};
    const float* mwt = wsf + OFF_MODWT;
    #pragma unroll
    for (int kd = 0; kd < 3; ++kd) {
        #pragma unroll
        for (int kh = 0; kh < 3; ++kh) {
            int cb = ((dl + kd)*6 + hh + kh)*67 + wx0;
            sv8 ck[6];
            #pragma unroll
            for (int s = 0; s < 6; ++s) ck[s] = tile[cb + s];
            float wv[6][8];
            #pragma unroll
            for (int s = 0; s < 6; ++s)
                #pragma unroll
                for (int c = 0; c < 8; ++c) wv[s][c] = b2f(ck[s][c]);
            #pragma unroll
            for (int kw = 0; kw < 3; ++kw) {
                const float* wrow = mwt + (kd*9 + kh*3 + kw)*DWC + g*8;
                #pragma unroll
                for (int c = 0; c < 8; ++c) {
                    float wgt = wrow[c];
                    #pragma unroll
                    for (int j = 0; j < 4; ++j)
                        acc[j][c] = fmaf(wgt, wv[j + kw][c], acc[j][c]);
                }
            }
        }
    }

    const float* smp = wsf + OFF_SMOD + b*DWC + g*8;
    const float* mbp = mod_b + g*8;
    sv8* adst = a + (size_t)(b*16 + g) * SPATIAL;
    float psum[8] = {};
    #pragma unroll
    for (int j = 0; j < 4; ++j) {
        sv8 ov;
        #pragma unroll
        for (int c = 0; c < 8; ++c) {
            float vv = gelu_f(fmaf(acc[j][c], smp[c], mbp[c]));
            psum[c] += vv;
            ov[c] = f2bs(vv);
        }
        adst[(d0 + dl)*4096 + (h0 + hh)*64 + wx0 + j] = ov;
    }
    #pragma unroll
    for (int c = 0; c < 8; ++c) {
        float v = psum[c];
        #pragma unroll
        for (int off = 32; off > 0; off >>= 1) v += __shfl_xor(v, off);
        if (lane == 0) atomicAdd(&pooled[b*DWC + g*8 + c], v);
    }
}

// ---------------- K3: SCA gate + fold into W3 (bf16) --------------------
__global__ void gate_kernel(const float* __restrict__ sca_w,
                            const float* __restrict__ sca_b,
                            const float* __restrict__ w3,
                            float* __restrict__ wsf) {
    __shared__ float gsh[256];
    int t = threadIdx.x;                  // 256
    int b = t >> 7, o = t & 127;
    const float invS = 1.f / (float)SPATIAL;
    float gval = sca_b[o];
    for (int i = 0; i < DWC; ++i)
        gval = fmaf(sca_w[o*DWC + i], wsf[OFF_POOLED + b*DWC + i] * invS, gval);
    wsf[OFF_GATE + t] = gval;
    gsh[t] = gval;
    __syncthreads();
    short* w3g = (short*)(wsf + OFF_U16) + U16_W3G;
    for (int idx = t; idx < 2*CH*DWC; idx += 256) {
        int bb = idx >> 13, rem = idx & 8191;
        int m = rem >> 7, k = rem & 127;
        w3g[idx] = f2bs(w3[m*DWC + k] * gsh[bb*DWC + k]);
    }
}

// ---------------- K4: pw3 + residual + LN2 + pw4 + GELU + pw5 (MFMA) ----
__global__ __launch_bounds__(256) void tail_kernel(const float* __restrict__ inp,
                                                   const sv8* __restrict__ a,
                                                   const float* __restrict__ wsf,
                                                   float* __restrict__ out) {
    __shared__ short yt[4][16*136];
    int blk = blockIdx.x;
    int b = blk >> 12;
    int vb = ((blk & 4095) << 6) + ((threadIdx.x >> 6) << 4);
    int lane = threadIdx.x & 63;
    int col = lane & 15, grp = lane >> 4;
    const short* w16 = (const short*)(wsf + OFF_U16);

    // pw3 B-fragments: direct b128 loads from a
    sv8 bq[4];
    #pragma unroll
    for (int ks = 0; ks < 4; ++ks)
        bq[ks] = a[(size_t)(b*16 + ks*4 + grp) * SPATIAL + vb + col];

    const sv8* W3 = (const sv8*)(w16 + U16_W3G) + (size_t)b * CH * 16;
    f32x4 acc3[4] = {};
    #pragma unroll
    for (int mt = 0; mt < 4; ++mt) {
        const sv8* wr = W3 + (mt*16 + col) * 16;
        #pragma unroll
        for (int ks = 0; ks < 4; ++ks)
            acc3[mt] = __builtin_amdgcn_mfma_f32_16x16x32_bf16(wr[grp + 4*ks], bq[ks], acc3[mt], 0, 0, 0);
    }

    // residual + LN2 stats
    const float4* pb35 = (const float4*)(wsf + OFF_PB35);
    float y[4][4];
    float sum = 0.f, ssq = 0.f;
    #pragma unroll
    for (int mt = 0; mt < 4; ++mt)
        #pragma unroll
        for (int r = 0; r < 4; ++r) {
            int c = mt*16 + 4*grp + r;
            float4 pb = pb35[c];
            float t = acc3[mt][r] + pb.x;
            float yv = fmaf(t, pb.y, inp[((size_t)b*CH + c)*SPATIAL + vb + col]);
            y[mt][r] = yv; sum += yv; ssq = fmaf(yv, yv, ssq);
        }
    sum += __shfl_xor(sum, 16); sum += __shfl_xor(sum, 32);
    ssq += __shfl_xor(ssq, 16); ssq += __shfl_xor(ssq, 32);
    float m2   = sum * (1.f/64.f);
    float var2 = fmaxf((ssq - 64.f*m2*m2) * (1.f/63.f), 0.f);
    float inv2 = 1.f / (sqrtf(var2) + 1e-6f);

    // y -> bf16 B-fragments via LDS transpose
    short* yw = &yt[threadIdx.x >> 6][0];
    #pragma unroll
    for (int mt = 0; mt < 4; ++mt) {
        sv4 p;
        #pragma unroll
        for (int r = 0; r < 4; ++r) p[r] = f2bs(y[mt][r]);
        *(sv4*)(yw + col*136 + mt*16 + 4*grp) = p;
    }
    sv8 by[2];
    #pragma unroll
    for (int ks = 0; ks < 2; ++ks)
        by[ks] = *(const sv8*)(yw + col*136 + grp*8 + ks*32);

    // pw4 (LN2 folded)
    const sv8* W4 = (const sv8*)(w16 + U16_W4B);
    f32x4 acc4[8] = {};
    #pragma unroll
    for (int mt = 0; mt < 8; ++mt) {
        const sv8* wr = W4 + (mt*16 + col) * 8;
        acc4[mt] = __builtin_amdgcn_mfma_f32_16x16x32_bf16(wr[grp],     by[0], acc4[mt], 0, 0, 0);
        acc4[mt] = __builtin_amdgcn_mfma_f32_16x16x32_bf16(wr[grp + 4], by[1], acc4[mt], 0, 0, 0);
    }

    // gelu -> bf16 B-fragments (reuse same LDS rows)
    const float2* pb4 = (const float2*)(wsf + OFF_PB4);
    #pragma unroll
    for (int mt = 0; mt < 8; ++mt) {
        sv4 p;
        #pragma unroll
        for (int r = 0; r < 4; ++r) {
            int f = mt*16 + 4*grp + r;
            float2 pb = pb4[f];
            float u = pb.x + inv2*(acc4[mt][r] - m2*pb.y);
            p[r] = f2bs(gelu_f(u));
        }
        *(sv4*)(yw + col*136 + mt*16 + 4*grp) = p;
    }
    sv8 bg[4];
    #pragma unroll
    for (int ks = 0; ks < 4; ++ks)
        bg[ks] = *(const sv8*)(yw + col*136 + grp*8 + ks*32);

    // pw5
    const sv8* W5 = (const sv8*)(w16 + U16_W5B);
    f32x4 acc5[4] = {};
    #pragma unroll
    for (int mt = 0; mt < 4; ++mt) {
        const sv8* wr = W5 + (mt*16 + col) * 16;
        #pragma unroll
        for (int ks = 0; ks < 4; ++ks)
            acc5[mt] = __builtin_amdgcn_mfma_f32_16x16x32_bf16(wr[grp + 4*ks], bg[ks], acc5[mt], 0, 0, 0);
    }

    #pragma unroll
    for (int mt = 0; mt < 4; ++mt)
        #pragma unroll
        for (int r = 0; r < 4; ++r) {
            int c = mt*16 + 4*grp + r;
            float4 pb = pb35[c];
            float o = fmaf(acc5[mt][r] + pb.w, pb.z, y[mt][r]);
            out[((size_t)b*CH + c)*SPATIAL + vb + col] = o;
        }
}

// ---------------- host launcher -----------------------------------------
extern "C" void kernel_launch(void* const* d_in, const int* in_sizes, int n_in,
                              void* d_out, int out_size, void* d_ws, size_t ws_size,
                              hipStream_t stream) {
    const float* inp     = (const float*)d_in[0];
    const float* style   = (const float*)d_in[1];
    const float* w1      = (const float*)d_in[2];
    const float* b1      = (const float*)d_in[3];
    const float* mod_w   = (const float*)d_in[4];
    const float* mod_b   = (const float*)d_in[5];
    const float* style_w = (const float*)d_in[6];
    const float* style_b = (const float*)d_in[7];
    const float* sca_w   = (const float*)d_in[8];
    const float* sca_b   = (const float*)d_in[9];
    const float* w3      = (const float*)d_in[10];
    const float* b3      = (const float*)d_in[11];
    const float* w4      = (const float*)d_in[12];
    const float* b4      = (const float*)d_in[13];
    const float* w5      = (const float*)d_in[14];
    const float* b5      = (const float*)d_in[15];
    const float* ln1w    = (const float*)d_in[16];
    const float* ln1b    = (const float*)d_in[17];
    const float* ln2w    = (const float*)d_in[18];
    const float* ln2b    = (const float*)d_in[19];
    const float* beta    = (const float*)d_in[20];
    const float* gamma   = (const float*)d_in[21];

    sv8*   h   = (sv8*)d_ws;
    sv8*   a   = (sv8*)((char*)d_ws + H_BYTES);
    float* wsf = (float*)((char*)d_ws + 2*H_BYTES);
    float* out = (float*)d_out;

    prep_kernel<<<1, 256, 0, stream>>>(style, w1, b1, mod_w, style_w, style_b,
                                       b3, w4, b4, w5, b5,
                                       ln1w, ln1b, ln2w, ln2b, beta, gamma, wsf);
    lnpw1_kernel<<<NVOX/64, 256, 0, stream>>>(inp, wsf, h);
    conv_kernel<<<8192, 256, 0, stream>>>(h, mod_b, wsf, a, wsf + OFF_POOLED);
    gate_kernel<<<1, 256, 0, stream>>>(sca_w, sca_b, w3, wsf);
    tail_kernel<<<NVOX/64, 256, 0, stream>>>(inp, a, wsf, out);
}

// Round 3
// 971.357 us; speedup vs baseline: 2.1381x; 2.1381x over previous
//
#include <hip/hip_runtime.h>
#include <hip/hip_bf16.h>

typedef __hip_bfloat16 bf16;
typedef short  sv4 __attribute__((ext_vector_type(4)));
typedef short  sv8 __attribute__((ext_vector_type(8)));
typedef float  f32x4 __attribute__((ext_vector_type(4)));

#define CH      64
#define DWC     128
#define SDIM    512
#define SPATIAL (64*64*64)     // 262144
#define NB      2
#define NVOX    (NB*SPATIAL)

// f32 workspace offsets (floats), area starts at d_ws + 2*H_BYTES
#define OFF_SMOD   0
#define OFF_POOLED 256
#define OFF_GATE   512
#define OFF_PB1    768     // (b1p, w1s) pairs [128]
#define OFF_PB4    1024    // (b4p, w4s) pairs [128]
#define OFF_PB35   1280    // (b3, beta, gamma, b5) quads [64]
#define OFF_MODWT  1536    // [27][128]
#define OFF_U16    5120    // start of bf16 weight area (in floats)
// u16 offsets from (short*)(wsf + OFF_U16)
#define U16_W1B 0          // [128][64]
#define U16_W3G 8192       // [2][64][128]  (gate-folded, per batch)
#define U16_W4B 24576      // [128][64]
#define U16_W5B 32768      // [64][128]

#define H_ELEMS ((size_t)NB * DWC * SPATIAL)
#define H_BYTES (H_ELEMS * 2)                 // 134,217,728

__device__ __forceinline__ float b2f(short u) {
    return __uint_as_float(((unsigned)(unsigned short)u) << 16);
}
__device__ __forceinline__ short f2bs(float f) {
    __hip_bfloat16 h = __float2bfloat16(f);
    return __builtin_bit_cast(short, h);
}
__device__ __forceinline__ float gelu_f(float x) {
    return 0.5f * x * (1.0f + erff(x * 0.70710678118654752f));
}

// ---------------- K0: prep -----------------------------------------------
__global__ void prep_kernel(const float* __restrict__ style,
                            const float* __restrict__ w1, const float* __restrict__ b1,
                            const float* __restrict__ mod_w,
                            const float* __restrict__ style_w, const float* __restrict__ style_b,
                            const float* __restrict__ b3,
                            const float* __restrict__ w4, const float* __restrict__ b4,
                            const float* __restrict__ w5, const float* __restrict__ b5,
                            const float* __restrict__ ln1w, const float* __restrict__ ln1b,
                            const float* __restrict__ ln2w, const float* __restrict__ ln2b,
                            const float* __restrict__ beta, const float* __restrict__ gamma,
                            float* __restrict__ wsf) {
    int t = threadIdx.x;   // 256 threads, 1 block
    short* w16 = (short*)(wsf + OFF_U16);
    {   // s*demod per (b, ch); zero pooled
        int b = t >> 7, ch = t & 127;
        float s = style_b[ch];
        for (int i = 0; i < SDIM; ++i) s = fmaf(style[b*SDIM + i], style_w[ch*SDIM + i], s);
        float k2 = 0.f;
        for (int j = 0; j < 27; ++j) { float w = mod_w[ch*27 + j]; k2 = fmaf(w, w, k2); }
        wsf[OFF_SMOD + t]   = s * rsqrtf(fmaf(k2, s*s, 1e-8f));
        wsf[OFF_POOLED + t] = 0.f;
    }
    if (t < DWC) {
        float bb1 = b1[t], ss1 = 0.f, bb4 = b4[t], ss4 = 0.f;
        for (int c = 0; c < CH; ++c) {
            bb1 = fmaf(w1[t*CH + c], ln1b[c], bb1);
            ss1 = fmaf(w1[t*CH + c], ln1w[c], ss1);
            bb4 = fmaf(w4[t*CH + c], ln2b[c], bb4);
            ss4 = fmaf(w4[t*CH + c], ln2w[c], ss4);
        }
        wsf[OFF_PB1 + 2*t] = bb1; wsf[OFF_PB1 + 2*t + 1] = ss1;
        wsf[OFF_PB4 + 2*t] = bb4; wsf[OFF_PB4 + 2*t + 1] = ss4;
    }
    if (t < CH) {
        wsf[OFF_PB35 + 4*t + 0] = b3[t];
        wsf[OFF_PB35 + 4*t + 1] = beta[t];
        wsf[OFF_PB35 + 4*t + 2] = gamma[t];
        wsf[OFF_PB35 + 4*t + 3] = b5[t];
    }
    for (int idx = t; idx < 27*DWC; idx += 256) {   // mod_w transpose [27][128]
        int k = idx >> 7, c = idx & 127;
        wsf[OFF_MODWT + idx] = mod_w[c*27 + k];
    }
    for (int idx = t; idx < DWC*CH; idx += 256) {   // bf16 weights
        int c = idx & 63;
        w16[U16_W1B + idx] = f2bs(w1[idx] * ln1w[c]);
        w16[U16_W4B + idx] = f2bs(w4[idx] * ln2w[c]);
        w16[U16_W5B + idx] = f2bs(w5[idx]);         // [64][128] row-major = [M][K]
    }
}

// ---------------- K1: LN1 + pw1 (MFMA) -> h [B][16g][v][8] bf16 ---------
__global__ __launch_bounds__(256) void lnpw1_kernel(const float* __restrict__ inp,
                                                    const float* __restrict__ wsf,
                                                    sv8* __restrict__ h) {
    __shared__ short ht[4][16*136];
    int blk = blockIdx.x;
    int b = blk >> 12;
    int vb = ((blk & 4095) << 6) + ((threadIdx.x >> 6) << 4);
    int lane = threadIdx.x & 63;
    int col = lane & 15, grp = lane >> 4;

    const float* xp = inp + (size_t)b * CH * SPATIAL + vb + col;
    float xv[16];
    float sum = 0.f, ssq = 0.f;
    #pragma unroll
    for (int e = 0; e < 16; ++e) {
        int k = ((e >> 3) << 5) + (grp << 3) + (e & 7);
        float t = xp[(size_t)k * SPATIAL];
        xv[e] = t; sum += t; ssq = fmaf(t, t, ssq);
    }
    sum += __shfl_xor(sum, 16); sum += __shfl_xor(sum, 32);
    ssq += __shfl_xor(ssq, 16); ssq += __shfl_xor(ssq, 32);
    float m   = sum * (1.f/64.f);
    float var = fmaxf((ssq - 64.f*m*m) * (1.f/63.f), 0.f);
    float inv = 1.f / (sqrtf(var) + 1e-6f);

    sv8 xb[2];
    #pragma unroll
    for (int ks = 0; ks < 2; ++ks)
        #pragma unroll
        for (int i = 0; i < 8; ++i) xb[ks][i] = f2bs(xv[ks*8 + i]);

    const sv8* W1 = (const sv8*)((const short*)(wsf + OFF_U16) + U16_W1B);
    f32x4 acc[8] = {};
    #pragma unroll
    for (int mt = 0; mt < 8; ++mt) {
        const sv8* wr = W1 + (mt*16 + col) * 8;
        acc[mt] = __builtin_amdgcn_mfma_f32_16x16x32_bf16(wr[grp],     xb[0], acc[mt], 0, 0, 0);
        acc[mt] = __builtin_amdgcn_mfma_f32_16x16x32_bf16(wr[grp + 4], xb[1], acc[mt], 0, 0, 0);
    }

    const float2* pb1 = (const float2*)(wsf + OFF_PB1);
    short* hw = &ht[threadIdx.x >> 6][0];
    #pragma unroll
    for (int mt = 0; mt < 8; ++mt) {
        sv4 p;
        #pragma unroll
        for (int r = 0; r < 4; ++r) {
            int f = mt*16 + 4*grp + r;
            float2 pb = pb1[f];
            p[r] = f2bs(pb.x + inv*(acc[mt][r] - m*pb.y));
        }
        *(sv4*)(hw + col*136 + mt*16 + 4*grp) = p;
    }
    #pragma unroll
    for (int gq = 0; gq < 4; ++gq) {
        int g = gq*4 + grp;
        sv8 vrow = *(const sv8*)(hw + col*136 + g*8);
        h[((size_t)(b*16 + g)) * SPATIAL + vb + col] = vrow;
    }
}

// ---------------- K2: depthwise 3x3x3 + mod + GELU -> a, pooled ---------
// No LDS: direct global stencil reads (L1/L2/L3 cached), one sv8 chunk
// (8 channels) per thread per step, 4 steps per thread.
__global__ __launch_bounds__(256) void conv_kernel(const sv8* __restrict__ h,
                                                   const float* __restrict__ mod_b,
                                                   const float* __restrict__ wsf,
                                                   sv8* __restrict__ a,
                                                   float* __restrict__ pooled) {
    __shared__ float part[4][8];
    int tid  = threadIdx.x;
    int lane = tid & 63;
    int bg   = blockIdx.x >> 8;            // (b*16+g), uniform per block
    int g    = bg & 15;
    int b    = bg >> 4;
    int vbase = (blockIdx.x & 255) << 10;  // 1024 chunks per block

    const sv8* hsrc = h + (size_t)bg * SPATIAL;
    sv8*       adst = a + (size_t)bg * SPATIAL;
    const float* mwt = wsf + OFF_MODWT + g*8;
    const float* smp = wsf + OFF_SMOD + b*DWC + g*8;
    const float* mbp = mod_b + g*8;

    float psum[8] = {};
    const sv8 zero = {0,0,0,0,0,0,0,0};

    #pragma unroll 1
    for (int j = 0; j < 4; ++j) {
        int v = vbase + j*256 + tid;
        int d  = v >> 12;
        int hy = (v >> 6) & 63;
        int w  = v & 63;

        float acc[8] = {};
        #pragma unroll
        for (int kd = 0; kd < 3; ++kd) {
            int dd = d + kd - 1;
            bool okd = (unsigned)dd < 64u;
            #pragma unroll
            for (int kh = 0; kh < 3; ++kh) {
                int hh = hy + kh - 1;
                bool ok = okd && ((unsigned)hh < 64u);
                const sv8* row = hsrc + dd*4096 + hh*64 + w;
                #pragma unroll
                for (int kw = 0; kw < 3; ++kw) {
                    int ww = w + kw - 1;
                    sv8 cv = (ok && (unsigned)ww < 64u) ? row[kw - 1] : zero;
                    const float* wr = mwt + (kd*9 + kh*3 + kw)*DWC;
                    #pragma unroll
                    for (int c = 0; c < 8; ++c)
                        acc[c] = fmaf(wr[c], b2f(cv[c]), acc[c]);
                }
            }
        }

        sv8 ov;
        #pragma unroll
        for (int c = 0; c < 8; ++c) {
            float vv = gelu_f(fmaf(acc[c], smp[c], mbp[c]));
            psum[c] += vv;
            ov[c] = f2bs(vv);
        }
        adst[v] = ov;
    }

    // reduce psum across the block -> 8 atomics
    #pragma unroll
    for (int c = 0; c < 8; ++c) {
        float s = psum[c];
        #pragma unroll
        for (int off = 32; off > 0; off >>= 1) s += __shfl_xor(s, off);
        if (lane == 0) part[tid >> 6][c] = s;
    }
    __syncthreads();
    if (tid < 8)
        atomicAdd(&pooled[b*DWC + g*8 + tid],
                  part[0][tid] + part[1][tid] + part[2][tid] + part[3][tid]);
}

// ---------------- K3: SCA gate + fold into W3 (bf16) --------------------
__global__ void gate_kernel(const float* __restrict__ sca_w,
                            const float* __restrict__ sca_b,
                            const float* __restrict__ w3,
                            float* __restrict__ wsf) {
    __shared__ float gsh[256];
    int t = threadIdx.x;                  // 256
    int b = t >> 7, o = t & 127;
    const float invS = 1.f / (float)SPATIAL;
    float gval = sca_b[o];
    for (int i = 0; i < DWC; ++i)
        gval = fmaf(sca_w[o*DWC + i], wsf[OFF_POOLED + b*DWC + i] * invS, gval);
    wsf[OFF_GATE + t] = gval;
    gsh[t] = gval;
    __syncthreads();
    short* w3g = (short*)(wsf + OFF_U16) + U16_W3G;
    for (int idx = t; idx < 2*CH*DWC; idx += 256) {
        int bb = idx >> 13, rem = idx & 8191;
        int m = rem >> 7, k = rem & 127;
        w3g[idx] = f2bs(w3[m*DWC + k] * gsh[bb*DWC + k]);
    }
}

// ---------------- K4: pw3 + residual + LN2 + pw4 + GELU + pw5 (MFMA) ----
__global__ __launch_bounds__(256) void tail_kernel(const float* __restrict__ inp,
                                                   const sv8* __restrict__ a,
                                                   const float* __restrict__ wsf,
                                                   float* __restrict__ out) {
    __shared__ short yt[4][16*136];
    int blk = blockIdx.x;
    int b = blk >> 12;
    int vb = ((blk & 4095) << 6) + ((threadIdx.x >> 6) << 4);
    int lane = threadIdx.x & 63;
    int col = lane & 15, grp = lane >> 4;
    const short* w16 = (const short*)(wsf + OFF_U16);

    // pw3 B-fragments: direct b128 loads from a
    sv8 bq[4];
    #pragma unroll
    for (int ks = 0; ks < 4; ++ks)
        bq[ks] = a[(size_t)(b*16 + ks*4 + grp) * SPATIAL + vb + col];

    const sv8* W3 = (const sv8*)(w16 + U16_W3G) + (size_t)b * CH * 16;
    f32x4 acc3[4] = {};
    #pragma unroll
    for (int mt = 0; mt < 4; ++mt) {
        const sv8* wr = W3 + (mt*16 + col) * 16;
        #pragma unroll
        for (int ks = 0; ks < 4; ++ks)
            acc3[mt] = __builtin_amdgcn_mfma_f32_16x16x32_bf16(wr[grp + 4*ks], bq[ks], acc3[mt], 0, 0, 0);
    }

    // residual + LN2 stats
    const float4* pb35 = (const float4*)(wsf + OFF_PB35);
    float y[4][4];
    float sum = 0.f, ssq = 0.f;
    #pragma unroll
    for (int mt = 0; mt < 4; ++mt)
        #pragma unroll
        for (int r = 0; r < 4; ++r) {
            int c = mt*16 + 4*grp + r;
            float4 pb = pb35[c];
            float t = acc3[mt][r] + pb.x;
            float yv = fmaf(t, pb.y, inp[((size_t)b*CH + c)*SPATIAL + vb + col]);
            y[mt][r] = yv; sum += yv; ssq = fmaf(yv, yv, ssq);
        }
    sum += __shfl_xor(sum, 16); sum += __shfl_xor(sum, 32);
    ssq += __shfl_xor(ssq, 16); ssq += __shfl_xor(ssq, 32);
    float m2   = sum * (1.f/64.f);
    float var2 = fmaxf((ssq - 64.f*m2*m2) * (1.f/63.f), 0.f);
    float inv2 = 1.f / (sqrtf(var2) + 1e-6f);

    // y -> bf16 B-fragments via LDS transpose
    short* yw = &yt[threadIdx.x >> 6][0];
    #pragma unroll
    for (int mt = 0; mt < 4; ++mt) {
        sv4 p;
        #pragma unroll
        for (int r = 0; r < 4; ++r) p[r] = f2bs(y[mt][r]);
        *(sv4*)(yw + col*136 + mt*16 + 4*grp) = p;
    }
    sv8 by[2];
    #pragma unroll
    for (int ks = 0; ks < 2; ++ks)
        by[ks] = *(const sv8*)(yw + col*136 + grp*8 + ks*32);

    // pw4 (LN2 folded)
    const sv8* W4 = (const sv8*)(w16 + U16_W4B);
    f32x4 acc4[8] = {};
    #pragma unroll
    for (int mt = 0; mt < 8; ++mt) {
        const sv8* wr = W4 + (mt*16 + col) * 8;
        acc4[mt] = __builtin_amdgcn_mfma_f32_16x16x32_bf16(wr[grp],     by[0], acc4[mt], 0, 0, 0);
        acc4[mt] = __builtin_amdgcn_mfma_f32_16x16x32_bf16(wr[grp + 4], by[1], acc4[mt], 0, 0, 0);
    }

    // gelu -> bf16 B-fragments (reuse same LDS rows)
    const float2* pb4 = (const float2*)(wsf + OFF_PB4);
    #pragma unroll
    for (int mt = 0; mt < 8; ++mt) {
        sv4 p;
        #pragma unroll
        for (int r = 0; r < 4; ++r) {
            int f = mt*16 + 4*grp + r;
            float2 pb = pb4[f];
            float u = pb.x + inv2*(acc4[mt][r] - m2*pb.y);
            p[r] = f2bs(gelu_f(u));
        }
        *(sv4*)(yw + col*136 + mt*16 + 4*grp) = p;
    }
    sv8 bg[4];
    #pragma unroll
    for (int ks = 0; ks < 4; ++ks)
        bg[ks] = *(const sv8*)(yw + col*136 + grp*8 + ks*32);

    // pw5
    const sv8* W5 = (const sv8*)(w16 + U16_W5B);
    f32x4 acc5[4] = {};
    #pragma unroll
    for (int mt = 0; mt < 4; ++mt) {
        const sv8* wr = W5 + (mt*16 + col) * 16;
        #pragma unroll
        for (int ks = 0; ks < 4; ++ks)
            acc5[mt] = __builtin_amdgcn_mfma_f32_16x16x32_bf16(wr[grp + 4*ks], bg[ks], acc5[mt], 0, 0, 0);
    }

    #pragma unroll
    for (int mt = 0; mt < 4; ++mt)
        #pragma unroll
        for (int r = 0; r < 4; ++r) {
            int c = mt*16 + 4*grp + r;
            float4 pb = pb35[c];
            float o = fmaf(acc5[mt][r] + pb.w, pb.z, y[mt][r]);
            out[((size_t)b*CH + c)*SPATIAL + vb + col] = o;
        }
}

// ---------------- host launcher -----------------------------------------
extern "C" void kernel_launch(void* const* d_in, const int* in_sizes, int n_in,
                              void* d_out, int out_size, void* d_ws, size_t ws_size,
                              hipStream_t stream) {
    const float* inp     = (const float*)d_in[0];
    const float* style   = (const float*)d_in[1];
    const float* w1      = (const float*)d_in[2];
    const float* b1      = (const float*)d_in[3];
    const float* mod_w   = (const float*)d_in[4];
    const float* mod_b   = (const float*)d_in[5];
    const float* style_w = (const float*)d_in[6];
    const float* style_b = (const float*)d_in[7];
    const float* sca_w   = (const float*)d_in[8];
    const float* sca_b   = (const float*)d_in[9];
    const float* w3      = (const float*)d_in[10];
    const float* b3      = (const float*)d_in[11];
    const float* w4      = (const float*)d_in[12];
    const float* b4      = (const float*)d_in[13];
    const float* w5      = (const float*)d_in[14];
    const float* b5      = (const float*)d_in[15];
    const float* ln1w    = (const float*)d_in[16];
    const float* ln1b    = (const float*)d_in[17];
    const float* ln2w    = (const float*)d_in[18];
    const float* ln2b    = (const float*)d_in[19];
    const float* beta    = (const float*)d_in[20];
    const float* gamma   = (const float*)d_in[21];

    sv8*   h   = (sv8*)d_ws;
    sv8*   a   = (sv8*)((char*)d_ws + H_BYTES);
    float* wsf = (float*)((char*)d_ws + 2*H_BYTES);
    float* out = (float*)d_out;

    prep_kernel<<<1, 256, 0, stream>>>(style, w1, b1, mod_w, style_w, style_b,
                                       b3, w4, b4, w5, b5,
                                       ln1w, ln1b, ln2w, ln2b, beta, gamma, wsf);
    lnpw1_kernel<<<NVOX/64, 256, 0, stream>>>(inp, wsf, h);
    conv_kernel<<<8192, 256, 0, stream>>>(h, mod_b, wsf, a, wsf + OFF_POOLED);
    gate_kernel<<<1, 256, 0, stream>>>(sca_w, sca_b, w3, wsf);
    tail_kernel<<<NVOX/64, 256, 0, stream>>>(inp, a, wsf, out);
}

// Round 4
// 660.809 us; speedup vs baseline: 3.1428x; 1.4700x over previous
//
#include <hip/hip_runtime.h>
#include <hip/hip_bf16.h>

typedef __hip_bfloat16 bf16;
typedef short  sv4 __attribute__((ext_vector_type(4)));
typedef short  sv8 __attribute__((ext_vector_type(8)));
typedef float  f32x4 __attribute__((ext_vector_type(4)));

#define CH      64
#define DWC     128
#define SDIM    512
#define SPATIAL (64*64*64)     // 262144
#define NB      2
#define NVOX    (NB*SPATIAL)

// padded h layout: per (b,g): [d][hy][65 chunks], chunk 0 of each row = zero pad
#define ROWS      65
#define PLANE_CH  (64*ROWS)          // 4160 chunks per d-plane
#define BG_CH     (64*PLANE_CH)      // 266240 chunks per (b,g)
#define HPAD_CHUNKS ((size_t)32*BG_CH + 16)   // +16 chunks slack (zeroed)
#define HPAD_BYTES  (HPAD_CHUNKS*16)

// f32 workspace offsets (floats), area starts after h + a
#define OFF_SMOD   0
#define OFF_POOLED 256
#define OFF_GATE   512
#define OFF_PB1    768     // (b1p, w1s) pairs [128]
#define OFF_PB4    1024    // (b4p, w4s) pairs [128]
#define OFF_PB35   1280    // (b3, beta, gamma, b5) quads [64]
#define OFF_MODWT  1536    // [27][128]
#define OFF_U16    5120    // start of bf16 weight area (in floats)
// u16 offsets from (short*)(wsf + OFF_U16)
#define U16_W1B 0          // [128][64]
#define U16_W3G 8192       // [2][64][128]  (gate-folded, per batch)
#define U16_W4B 24576      // [128][64]
#define U16_W5B 32768      // [64][128]

#define A_BYTES ((size_t)NB * DWC * SPATIAL * 2)   // 134,217,728

__device__ __forceinline__ float b2f(short u) {
    return __uint_as_float(((unsigned)(unsigned short)u) << 16);
}
__device__ __forceinline__ short f2bs(float f) {
    __hip_bfloat16 h = __float2bfloat16(f);
    return __builtin_bit_cast(short, h);
}
__device__ __forceinline__ float gelu_f(float x) {
    return 0.5f * x * (1.0f + erff(x * 0.70710678118654752f));
}

// ---------------- K0: prep -----------------------------------------------
__global__ void prep_kernel(const float* __restrict__ style,
                            const float* __restrict__ w1, const float* __restrict__ b1,
                            const float* __restrict__ mod_w,
                            const float* __restrict__ style_w, const float* __restrict__ style_b,
                            const float* __restrict__ b3,
                            const float* __restrict__ w4, const float* __restrict__ b4,
                            const float* __restrict__ w5, const float* __restrict__ b5,
                            const float* __restrict__ ln1w, const float* __restrict__ ln1b,
                            const float* __restrict__ ln2w, const float* __restrict__ ln2b,
                            const float* __restrict__ beta, const float* __restrict__ gamma,
                            float* __restrict__ wsf, sv8* __restrict__ h) {
    int t = threadIdx.x;   // 256 threads, 1 block
    short* w16 = (short*)(wsf + OFF_U16);
    if (t < 16) {          // zero the slack chunks past the padded h buffer
        const sv8 zz = {0,0,0,0,0,0,0,0};
        h[(size_t)32*BG_CH + t] = zz;
    }
    {   // s*demod per (b, ch); zero pooled
        int b = t >> 7, ch = t & 127;
        float s = style_b[ch];
        for (int i = 0; i < SDIM; ++i) s = fmaf(style[b*SDIM + i], style_w[ch*SDIM + i], s);
        float k2 = 0.f;
        for (int j = 0; j < 27; ++j) { float w = mod_w[ch*27 + j]; k2 = fmaf(w, w, k2); }
        wsf[OFF_SMOD + t]   = s * rsqrtf(fmaf(k2, s*s, 1e-8f));
        wsf[OFF_POOLED + t] = 0.f;
    }
    if (t < DWC) {
        float bb1 = b1[t], ss1 = 0.f, bb4 = b4[t], ss4 = 0.f;
        for (int c = 0; c < CH; ++c) {
            bb1 = fmaf(w1[t*CH + c], ln1b[c], bb1);
            ss1 = fmaf(w1[t*CH + c], ln1w[c], ss1);
            bb4 = fmaf(w4[t*CH + c], ln2b[c], bb4);
            ss4 = fmaf(w4[t*CH + c], ln2w[c], ss4);
        }
        wsf[OFF_PB1 + 2*t] = bb1; wsf[OFF_PB1 + 2*t + 1] = ss1;
        wsf[OFF_PB4 + 2*t] = bb4; wsf[OFF_PB4 + 2*t + 1] = ss4;
    }
    if (t < CH) {
        wsf[OFF_PB35 + 4*t + 0] = b3[t];
        wsf[OFF_PB35 + 4*t + 1] = beta[t];
        wsf[OFF_PB35 + 4*t + 2] = gamma[t];
        wsf[OFF_PB35 + 4*t + 3] = b5[t];
    }
    for (int idx = t; idx < 27*DWC; idx += 256) {   // mod_w transpose [27][128]
        int k = idx >> 7, c = idx & 127;
        wsf[OFF_MODWT + idx] = mod_w[c*27 + k];
    }
    for (int idx = t; idx < DWC*CH; idx += 256) {   // bf16 weights
        int c = idx & 63;
        w16[U16_W1B + idx] = f2bs(w1[idx] * ln1w[c]);
        w16[U16_W4B + idx] = f2bs(w4[idx] * ln2w[c]);
        w16[U16_W5B + idx] = f2bs(w5[idx]);         // [64][128] row-major = [M][K]
    }
}

// ---------------- K1: LN1 + pw1 (MFMA) -> h padded layout ----------------
__global__ __launch_bounds__(256) void lnpw1_kernel(const float* __restrict__ inp,
                                                    const float* __restrict__ wsf,
                                                    sv8* __restrict__ h) {
    __shared__ short ht[4][16*136];
    int blk = blockIdx.x;
    int b = blk >> 12;
    int vb = ((blk & 4095) << 6) + ((threadIdx.x >> 6) << 4);
    int lane = threadIdx.x & 63;
    int col = lane & 15, grp = lane >> 4;

    const float* xp = inp + (size_t)b * CH * SPATIAL + vb + col;
    float xv[16];
    float sum = 0.f, ssq = 0.f;
    #pragma unroll
    for (int e = 0; e < 16; ++e) {
        int k = ((e >> 3) << 5) + (grp << 3) + (e & 7);
        float t = xp[(size_t)k * SPATIAL];
        xv[e] = t; sum += t; ssq = fmaf(t, t, ssq);
    }
    sum += __shfl_xor(sum, 16); sum += __shfl_xor(sum, 32);
    ssq += __shfl_xor(ssq, 16); ssq += __shfl_xor(ssq, 32);
    float m   = sum * (1.f/64.f);
    float var = fmaxf((ssq - 64.f*m*m) * (1.f/63.f), 0.f);
    float inv = 1.f / (sqrtf(var) + 1e-6f);

    sv8 xb[2];
    #pragma unroll
    for (int ks = 0; ks < 2; ++ks)
        #pragma unroll
        for (int i = 0; i < 8; ++i) xb[ks][i] = f2bs(xv[ks*8 + i]);

    const sv8* W1 = (const sv8*)((const short*)(wsf + OFF_U16) + U16_W1B);
    f32x4 acc[8] = {};
    #pragma unroll
    for (int mt = 0; mt < 8; ++mt) {
        const sv8* wr = W1 + (mt*16 + col) * 8;
        acc[mt] = __builtin_amdgcn_mfma_f32_16x16x32_bf16(wr[grp],     xb[0], acc[mt], 0, 0, 0);
        acc[mt] = __builtin_amdgcn_mfma_f32_16x16x32_bf16(wr[grp + 4], xb[1], acc[mt], 0, 0, 0);
    }

    const float2* pb1 = (const float2*)(wsf + OFF_PB1);
    short* hw = &ht[threadIdx.x >> 6][0];
    #pragma unroll
    for (int mt = 0; mt < 8; ++mt) {
        sv4 p;
        #pragma unroll
        for (int r = 0; r < 4; ++r) {
            int f = mt*16 + 4*grp + r;
            float2 pb = pb1[f];
            p[r] = f2bs(pb.x + inv*(acc[mt][r] - m*pb.y));
        }
        *(sv4*)(hw + col*136 + mt*16 + 4*grp) = p;
    }
    int row = vb >> 6;      // (d*64 + hy), uniform per block
    int wlo = vb & 63;      // wave's w offset within the row
    #pragma unroll
    for (int gq = 0; gq < 4; ++gq) {
        int g = gq*4 + grp;
        sv8 vrow = *(const sv8*)(hw + col*136 + g*8);
        size_t base = (size_t)(b*16 + g) * BG_CH + row*ROWS;
        h[base + 1 + wlo + col] = vrow;
        if (wlo == 0 && col == 0) {          // zero this row's pad chunk
            const sv8 zz = {0,0,0,0,0,0,0,0};
            h[base] = zz;
        }
    }
}

// ---------------- K2: depthwise 3x3x3 + mod + GELU -> a, pooled ---------
// d-column register blocking (16 outputs/thread), rolling 3-deep acc.
// w bounds handled by stride-65 zero-pad; hy/d bounds are uniform branches.
__global__ __launch_bounds__(256) void conv_kernel(const sv8* __restrict__ h,
                                                   const float* __restrict__ mod_b,
                                                   const float* __restrict__ wsf,
                                                   sv8* __restrict__ a,
                                                   float* __restrict__ pooled) {
    __shared__ float part[4][8];
    int tid = threadIdx.x;
    int w   = tid & 63;
    int dq  = tid >> 6;            // wave id: d-quadrant
    int hy  = blockIdx.x & 63;
    int bg  = blockIdx.x >> 6;     // 0..31
    int g   = bg & 15;
    int b   = bg >> 4;

    const sv8* hP  = h + (size_t)bg * BG_CH;
    sv8*      adst = a + (size_t)bg * SPATIAL;
    const float* mwt = wsf + OFF_MODWT + g*8;     // W[k][c] at mwt[k*128 + c]
    const float* smp = wsf + OFF_SMOD + b*DWC + g*8;
    const float* mbp = mod_b + g*8;

    bool r0ok = (hy > 0), r2ok = (hy < 63);
    int d0 = dq << 4;

    float an[8] = {}, am[8] = {}, ao[8] = {};
    float psum[8] = {};

    #pragma unroll 1
    for (int i = 0; i < 18; ++i) {
        int dd = d0 - 1 + i;
        float f[9][8];
        if ((unsigned)dd < 64u) {
            const sv8* p = hP + dd*PLANE_CH + hy*ROWS + 1 + w;
            sv8 cv[9];
            const sv8 zz = {0,0,0,0,0,0,0,0};
            if (r0ok) { cv[0] = p[-ROWS-1]; cv[1] = p[-ROWS]; cv[2] = p[-ROWS+1]; }
            else      { cv[0] = zz; cv[1] = zz; cv[2] = zz; }
            cv[3] = p[-1]; cv[4] = p[0]; cv[5] = p[1];
            if (r2ok) { cv[6] = p[ROWS-1]; cv[7] = p[ROWS]; cv[8] = p[ROWS+1]; }
            else      { cv[6] = zz; cv[7] = zz; cv[8] = zz; }
            #pragma unroll
            for (int r = 0; r < 9; ++r)
                #pragma unroll
                for (int c = 0; c < 8; ++c) f[r][c] = b2f(cv[r][c]);
        } else {
            #pragma unroll
            for (int r = 0; r < 9; ++r)
                #pragma unroll
                for (int c = 0; c < 8; ++c) f[r][c] = 0.f;
        }

        if (i >= 2) {                       // old: output o = d0+i-2, kd=2
            #pragma unroll
            for (int r = 0; r < 9; ++r) {
                const float* wr = mwt + (18 + r)*DWC;
                #pragma unroll
                for (int c = 0; c < 8; ++c) ao[c] = fmaf(wr[c], f[r][c], ao[c]);
            }
            int o = d0 + i - 2;
            sv8 ov;
            #pragma unroll
            for (int c = 0; c < 8; ++c) {
                float vv = gelu_f(fmaf(ao[c], smp[c], mbp[c]));
                psum[c] += vv;
                ov[c] = f2bs(vv);
            }
            adst[o*4096 + hy*64 + w] = ov;
        }
        if (i >= 1 && i <= 16) {            // mid: output o = d0+i-1, kd=1
            #pragma unroll
            for (int r = 0; r < 9; ++r) {
                const float* wr = mwt + (9 + r)*DWC;
                #pragma unroll
                for (int c = 0; c < 8; ++c) am[c] = fmaf(wr[c], f[r][c], am[c]);
            }
        }
        if (i <= 15) {                      // new: output o = d0+i, kd=0
            #pragma unroll
            for (int c = 0; c < 8; ++c) an[c] = 0.f;
            #pragma unroll
            for (int r = 0; r < 9; ++r) {
                const float* wr = mwt + r*DWC;
                #pragma unroll
                for (int c = 0; c < 8; ++c) an[c] = fmaf(wr[c], f[r][c], an[c]);
            }
        }
        #pragma unroll
        for (int c = 0; c < 8; ++c) { ao[c] = am[c]; am[c] = an[c]; }
    }

    // block reduction of psum -> 8 atomics
    #pragma unroll
    for (int c = 0; c < 8; ++c) {
        float s = psum[c];
        #pragma unroll
        for (int off = 32; off > 0; off >>= 1) s += __shfl_xor(s, off);
        if ((tid & 63) == 0) part[dq][c] = s;
    }
    __syncthreads();
    if (tid < 8)
        atomicAdd(&pooled[b*DWC + g*8 + tid],
                  part[0][tid] + part[1][tid] + part[2][tid] + part[3][tid]);
}

// ---------------- K3: SCA gate + fold into W3 (bf16) --------------------
__global__ void gate_kernel(const float* __restrict__ sca_w,
                            const float* __restrict__ sca_b,
                            const float* __restrict__ w3,
                            float* __restrict__ wsf) {
    __shared__ float gsh[256];
    int t = threadIdx.x;                  // 256
    int b = t >> 7, o = t & 127;
    const float invS = 1.f / (float)SPATIAL;
    float gval = sca_b[o];
    for (int i = 0; i < DWC; ++i)
        gval = fmaf(sca_w[o*DWC + i], wsf[OFF_POOLED + b*DWC + i] * invS, gval);
    wsf[OFF_GATE + t] = gval;
    gsh[t] = gval;
    __syncthreads();
    short* w3g = (short*)(wsf + OFF_U16) + U16_W3G;
    for (int idx = t; idx < 2*CH*DWC; idx += 256) {
        int bb = idx >> 13, rem = idx & 8191;
        int m = rem >> 7, k = rem & 127;
        w3g[idx] = f2bs(w3[m*DWC + k] * gsh[bb*DWC + k]);
    }
}

// ---------------- K4: pw3 + residual + LN2 + pw4 + GELU + pw5 (MFMA) ----
__global__ __launch_bounds__(256) void tail_kernel(const float* __restrict__ inp,
                                                   const sv8* __restrict__ a,
                                                   const float* __restrict__ wsf,
                                                   float* __restrict__ out) {
    __shared__ short yt[4][16*136];
    int blk = blockIdx.x;
    int b = blk >> 12;
    int vb = ((blk & 4095) << 6) + ((threadIdx.x >> 6) << 4);
    int lane = threadIdx.x & 63;
    int col = lane & 15, grp = lane >> 4;
    const short* w16 = (const short*)(wsf + OFF_U16);

    // pw3 B-fragments: direct b128 loads from a
    sv8 bq[4];
    #pragma unroll
    for (int ks = 0; ks < 4; ++ks)
        bq[ks] = a[(size_t)(b*16 + ks*4 + grp) * SPATIAL + vb + col];

    const sv8* W3 = (const sv8*)(w16 + U16_W3G) + (size_t)b * CH * 16;
    f32x4 acc3[4] = {};
    #pragma unroll
    for (int mt = 0; mt < 4; ++mt) {
        const sv8* wr = W3 + (mt*16 + col) * 16;
        #pragma unroll
        for (int ks = 0; ks < 4; ++ks)
            acc3[mt] = __builtin_amdgcn_mfma_f32_16x16x32_bf16(wr[grp + 4*ks], bq[ks], acc3[mt], 0, 0, 0);
    }

    // residual + LN2 stats
    const float4* pb35 = (const float4*)(wsf + OFF_PB35);
    float y[4][4];
    float sum = 0.f, ssq = 0.f;
    #pragma unroll
    for (int mt = 0; mt < 4; ++mt)
        #pragma unroll
        for (int r = 0; r < 4; ++r) {
            int c = mt*16 + 4*grp + r;
            float4 pb = pb35[c];
            float t = acc3[mt][r] + pb.x;
            float yv = fmaf(t, pb.y, inp[((size_t)b*CH + c)*SPATIAL + vb + col]);
            y[mt][r] = yv; sum += yv; ssq = fmaf(yv, yv, ssq);
        }
    sum += __shfl_xor(sum, 16); sum += __shfl_xor(sum, 32);
    ssq += __shfl_xor(ssq, 16); ssq += __shfl_xor(ssq, 32);
    float m2   = sum * (1.f/64.f);
    float var2 = fmaxf((ssq - 64.f*m2*m2) * (1.f/63.f), 0.f);
    float inv2 = 1.f / (sqrtf(var2) + 1e-6f);

    // y -> bf16 B-fragments via LDS transpose
    short* yw = &yt[threadIdx.x >> 6][0];
    #pragma unroll
    for (int mt = 0; mt < 4; ++mt) {
        sv4 p;
        #pragma unroll
        for (int r = 0; r < 4; ++r) p[r] = f2bs(y[mt][r]);
        *(sv4*)(yw + col*136 + mt*16 + 4*grp) = p;
    }
    sv8 by[2];
    #pragma unroll
    for (int ks = 0; ks < 2; ++ks)
        by[ks] = *(const sv8*)(yw + col*136 + grp*8 + ks*32);

    // pw4 (LN2 folded)
    const sv8* W4 = (const sv8*)(w16 + U16_W4B);
    f32x4 acc4[8] = {};
    #pragma unroll
    for (int mt = 0; mt < 8; ++mt) {
        const sv8* wr = W4 + (mt*16 + col) * 8;
        acc4[mt] = __builtin_amdgcn_mfma_f32_16x16x32_bf16(wr[grp],     by[0], acc4[mt], 0, 0, 0);
        acc4[mt] = __builtin_amdgcn_mfma_f32_16x16x32_bf16(wr[grp + 4], by[1], acc4[mt], 0, 0, 0);
    }

    // gelu -> bf16 B-fragments (reuse same LDS rows)
    const float2* pb4 = (const float2*)(wsf + OFF_PB4);
    #pragma unroll
    for (int mt = 0; mt < 8; ++mt) {
        sv4 p;
        #pragma unroll
        for (int r = 0; r < 4; ++r) {
            int f = mt*16 + 4*grp + r;
            float2 pb = pb4[f];
            float u = pb.x + inv2*(acc4[mt][r] - m2*pb.y);
            p[r] = f2bs(gelu_f(u));
        }
        *(sv4*)(yw + col*136 + mt*16 + 4*grp) = p;
    }
    sv8 bg[4];
    #pragma unroll
    for (int ks = 0; ks < 4; ++ks)
        bg[ks] = *(const sv8*)(yw + col*136 + grp*8 + ks*32);

    // pw5
    const sv8* W5 = (const sv8*)(w16 + U16_W5B);
    f32x4 acc5[4] = {};
    #pragma unroll
    for (int mt = 0; mt < 4; ++mt) {
        const sv8* wr = W5 + (mt*16 + col) * 16;
        #pragma unroll
        for (int ks = 0; ks < 4; ++ks)
            acc5[mt] = __builtin_amdgcn_mfma_f32_16x16x32_bf16(wr[grp + 4*ks], bg[ks], acc5[mt], 0, 0, 0);
    }

    #pragma unroll
    for (int mt = 0; mt < 4; ++mt)
        #pragma unroll
        for (int r = 0; r < 4; ++r) {
            int c = mt*16 + 4*grp + r;
            float4 pb = pb35[c];
            float o = fmaf(acc5[mt][r] + pb.w, pb.z, y[mt][r]);
            out[((size_t)b*CH + c)*SPATIAL + vb + col] = o;
        }
}

// ---------------- host launcher -----------------------------------------
extern "C" void kernel_launch(void* const* d_in, const int* in_sizes, int n_in,
                              void* d_out, int out_size, void* d_ws, size_t ws_size,
                              hipStream_t stream) {
    const float* inp     = (const float*)d_in[0];
    const float* style   = (const float*)d_in[1];
    const float* w1      = (const float*)d_in[2];
    const float* b1      = (const float*)d_in[3];
    const float* mod_w   = (const float*)d_in[4];
    const float* mod_b   = (const float*)d_in[5];
    const float* style_w = (const float*)d_in[6];
    const float* style_b = (const float*)d_in[7];
    const float* sca_w   = (const float*)d_in[8];
    const float* sca_b   = (const float*)d_in[9];
    const float* w3      = (const float*)d_in[10];
    const float* b3      = (const float*)d_in[11];
    const float* w4      = (const float*)d_in[12];
    const float* b4      = (const float*)d_in[13];
    const float* w5      = (const float*)d_in[14];
    const float* b5      = (const float*)d_in[15];
    const float* ln1w    = (const float*)d_in[16];
    const float* ln1b    = (const float*)d_in[17];
    const float* ln2w    = (const float*)d_in[18];
    const float* ln2b    = (const float*)d_in[19];
    const float* beta    = (const float*)d_in[20];
    const float* gamma   = (const float*)d_in[21];

    sv8*   h   = (sv8*)d_ws;
    sv8*   a   = (sv8*)((char*)d_ws + HPAD_BYTES);
    float* wsf = (float*)((char*)d_ws + HPAD_BYTES + A_BYTES);
    float* out = (float*)d_out;

    prep_kernel<<<1, 256, 0, stream>>>(style, w1, b1, mod_w, style_w, style_b,
                                       b3, w4, b4, w5, b5,
                                       ln1w, ln1b, ln2w, ln2b, beta, gamma, wsf, h);
    lnpw1_kernel<<<NVOX/64, 256, 0, stream>>>(inp, wsf, h);
    conv_kernel<<<2048, 256, 0, stream>>>(h, mod_b, wsf, a, wsf + OFF_POOLED);
    gate_kernel<<<1, 256, 0, stream>>>(sca_w, sca_b, w3, wsf);
    tail_kernel<<<NVOX/64, 256, 0, stream>>>(inp, a, wsf, out);
}